// Round 16
// baseline (2093.324 us; speedup 1.0000x reference)
//
#include <hip/hip_runtime.h>

// ---------------- constants ----------------
#define HDIM 1024
#define BB 8
#define SS 1024
#define NHEAD 16
#define PFF 4096
#define NLAYER 6
#define MM (BB*SS)   // 8192 rows

typedef __attribute__((ext_vector_type(8))) short bf16x8_t;
typedef __attribute__((ext_vector_type(4))) float f32x4_t;
typedef __attribute__((ext_vector_type(16))) float f32x16_t;

static __device__ __forceinline__ unsigned short f2b(float f) {
  unsigned int u = __float_as_uint(f);
  u += 0x7fffu + ((u >> 16) & 1u);      // RNE
  return (unsigned short)(u >> 16);
}

static __device__ __forceinline__ float b2f(unsigned short u) {
  return __uint_as_float(((unsigned)u) << 16);
}

static __device__ __forceinline__ unsigned pkbf(float lo, float hi) {
  unsigned r;
  asm("v_cvt_pk_bf16_f32 %0, %1, %2" : "=v"(r) : "v"(lo), "v"(hi));
  return r;
}

static __device__ __forceinline__ bf16x8_t mk8(unsigned a, unsigned b, unsigned c, unsigned d) {
  union { unsigned u[4]; bf16x8_t v; } x;
  x.u[0] = a; x.u[1] = b; x.u[2] = c; x.u[3] = d;
  return x.v;
}

static __device__ __forceinline__ void gload16(const void* g, void* l) {
  __builtin_amdgcn_global_load_lds((__attribute__((address_space(1))) void*)g,
                                   (__attribute__((address_space(3))) void*)l, 16, 0, 0);
}

template<int N>
static __device__ __forceinline__ void vwait() {
  asm volatile("s_waitcnt vmcnt(%0)" :: "n"(N) : "memory");
}

static __device__ __forceinline__ void bar() {
  asm volatile("" ::: "memory");
  __builtin_amdgcn_s_barrier();
  asm volatile("" ::: "memory");
}

// ---------------- fp32 -> bf16 convert ----------------
__global__ __launch_bounds__(256) void cvt_bf16(const float* __restrict__ in,
                                                unsigned short* __restrict__ o, int n4) {
  const int i = blockIdx.x * 256 + threadIdx.x;
  if (i < n4) {
    const float4 v = ((const float4*)in)[i];
    ushort4 ob = { f2b(v.x), f2b(v.y), f2b(v.z), f2b(v.w) };
    ((ushort4*)o)[i] = ob;
  }
}

// ---------------- transpose fp32 [R][C] -> bf16 [C][R] (emb prep only) ----------------
__global__ __launch_bounds__(256) void transpose_bf16(const float* __restrict__ in,
                                                      unsigned short* __restrict__ outT,
                                                      int R, int C) {
  __shared__ float tile[32][33];
  const int c0 = blockIdx.x * 32, r0 = blockIdx.y * 32;
  const int tx = threadIdx.x, ty = threadIdx.y;   // (32,8)
#pragma unroll
  for (int i = 0; i < 4; ++i)
    tile[ty + 8*i][tx] = in[(size_t)(r0 + ty + 8*i) * C + c0 + tx];
  __syncthreads();
#pragma unroll
  for (int i = 0; i < 4; ++i)
    outT[(size_t)(c0 + ty + 8*i) * R + r0 + tx] = f2b(tile[tx][ty + 8*i]);
}

// ---------------- per-layer prep: 6 weight transposes + bias concat in ONE launch ----------------
__global__ __launch_bounds__(256) void prep_layer(
    const float* __restrict__ Wq, const float* __restrict__ Wk,
    const float* __restrict__ Wv, const float* __restrict__ Wo,
    const float* __restrict__ W1, const float* __restrict__ W2,
    const float* __restrict__ bq, const float* __restrict__ bk,
    const float* __restrict__ bv,
    unsigned short* __restrict__ wqkvT, unsigned short* __restrict__ woT,
    unsigned short* __restrict__ w1T, unsigned short* __restrict__ w2T,
    float* __restrict__ bqkv) {
  const int id = blockIdx.x;
  const int tx = threadIdx.x, ty = threadIdx.y;   // (32,8)
  if (id >= 12288) {                               // bias concat (12 blocks x 256)
    const int i = (id - 12288) * 256 + ty * 32 + tx;
    bqkv[i] = (i < 1024) ? bq[i] : ((i < 2048) ? bk[i - 1024] : bv[i - 2048]);
    return;
  }
  __shared__ float tile[32][33];
  const float* in; unsigned short* outp; int R, C, tid;
  if (id < 1024)      { in = Wq; outp = wqkvT;           R = 1024; C = 1024; tid = id; }
  else if (id < 2048) { in = Wk; outp = wqkvT + 1048576; R = 1024; C = 1024; tid = id - 1024; }
  else if (id < 3072) { in = Wv; outp = wqkvT + 2097152; R = 1024; C = 1024; tid = id - 2048; }
  else if (id < 4096) { in = Wo; outp = woT;             R = 1024; C = 1024; tid = id - 3072; }
  else if (id < 8192) { in = W1; outp = w1T;             R = 1024; C = 4096; tid = id - 4096; }
  else                { in = W2; outp = w2T;             R = 4096; C = 1024; tid = id - 8192; }
  const int gxn = C >> 5;
  const int c0 = (tid % gxn) * 32, r0 = (tid / gxn) * 32;
#pragma unroll
  for (int i = 0; i < 4; ++i)
    tile[ty + 8*i][tx] = in[(size_t)(r0 + ty + 8*i) * C + c0 + tx];
  __syncthreads();
#pragma unroll
  for (int i = 0; i < 4; ++i)
    outp[(size_t)(c0 + ty + 8*i) * R + r0 + tx] = f2b(tile[tx][ty + 8*i]);
}

// ---------------- GEMM 256xBN, 8 waves (2x4), 16x16x32, pipelined 2-barrier K-tile ----------------
// R6/R8/R10-R15-verified schedule. BN in {128,192,256}.
template<int BN, bool BIAS, bool RELU, bool RESID, bool EMB, bool WF32, bool WBF16, bool VTW>
__global__ __launch_bounds__(512, 2) void gemm2c(
    const unsigned short* __restrict__ A,
    const unsigned short* __restrict__ Bt,
    const float* __restrict__ bias,
    const unsigned short* __restrict__ resid,   // bf16 residual stream
    const float* __restrict__ pos,
    float* __restrict__ outf,
    unsigned short* __restrict__ outb,
    unsigned short* __restrict__ vtw,
    int M, int N, int K) {
  constexpr int NJ = BN / 64;                    // B frags per wave (4, 3 or 2)
  constexpr int WCN = BN / 4;                    // per-wave col span
  constexpr int BUFSZ = 32768 + BN * 128;
  __shared__ __align__(1024) char smem[2 * BUFSZ];
  const int t = threadIdx.x, lane = t & 63, w = t >> 6;
  const int wr = w >> 2, wc = w & 3;             // 2x4 wave grid

  // bijective XCD swizzle (all grids divisible by 8)
  int flat = blockIdx.x + gridDim.x * blockIdx.y;
  const int cpx = (gridDim.x * gridDim.y) >> 3;
  flat = (flat & 7) * cpx + (flat >> 3);
  const int m0 = (flat / gridDim.x) * 256;
  const int n0 = (flat % gridDim.x) * BN;

  const f32x4_t z = {0.f, 0.f, 0.f, 0.f};
  f32x4_t acc[8][NJ];
#pragma unroll
  for (int i = 0; i < 8; ++i)
#pragma unroll
    for (int j = 0; j < NJ; ++j) acc[i][j] = z;

  auto stageA = [&](int i, int kt, int buf) {
    const int chunk = i * 8 + w;                 // band i = rows [64*i, +64)
    const int byteoff = chunk * 1024 + lane * 16;
    const int row = byteoff >> 7;
    const int scb = (byteoff & 127) ^ ((row & 7) << 4);
    gload16((const char*)A + ((size_t)(m0 + row) * K + (kt << 6)) * 2 + scb,
            smem + buf * BUFSZ + chunk * 1024);
  };
  auto stageB = [&](int i, int kt, int buf) {
    const int chunk = i * 8 + w;
    const int byteoff = chunk * 1024 + lane * 16;
    const int row = byteoff >> 7;
    const int scb = (byteoff & 127) ^ ((row & 7) << 4);
    gload16((const char*)Bt + ((size_t)(n0 + row) * K + (kt << 6)) * 2 + scb,
            smem + buf * BUFSZ + 32768 + chunk * 1024);
  };
  auto readA = [&](const char* ab, int fi, int ks) {
    const int row = wr * 128 + fi * 16 + (lane & 15);
    const int cb = ks * 64 + ((lane >> 4) << 4);
    return *(const bf16x8_t*)(ab + row * 128 + (cb ^ ((row & 7) << 4)));
  };
  auto readB = [&](const char* bb, int j, int ks) {
    const int row = wc * WCN + j * 16 + (lane & 15);
    const int cb = ks * 64 + ((lane >> 4) << 4);
    return *(const bf16x8_t*)(bb + row * 128 + (cb ^ ((row & 7) << 4)));
  };

  // prologue: tile 0 in need-order (B*, A0, A2, A1, A3)
  stageB(0, 0, 0); stageB(1, 0, 0);
  if constexpr (NJ >= 3) stageB(2, 0, 0);
  if constexpr (NJ >= 4) stageB(3, 0, 0);
  stageA(0, 0, 0); stageA(2, 0, 0); stageA(1, 0, 0); stageA(3, 0, 0);

  const int nkt = K >> 6;
  for (int kt = 0; kt < nkt; ++kt) {
    const char* ab = smem + (kt & 1) * BUFSZ;
    const char* bb = ab + 32768;
    const int nb = (kt & 1) ^ 1;
    const bool pf = (kt + 1 < nkt);
    bf16x8_t bfr[NJ][2], af[8][2];

    if constexpr (BN >= 192) {
      // ---- ph0: certify {B*,A0,A2}; read B + frags0-3; MFMA 0-1 ----
      vwait<2>(); bar();
      if (pf) { stageB(0, kt + 1, nb); stageB(1, kt + 1, nb); }
#pragma unroll
      for (int j = 0; j < NJ; ++j)
#pragma unroll
        for (int ks = 0; ks < 2; ++ks) bfr[j][ks] = readB(bb, j, ks);
#pragma unroll
      for (int d = 0; d < 4; ++d)
#pragma unroll
        for (int ks = 0; ks < 2; ++ks) af[d][ks] = readA(ab, d, ks);
      __builtin_amdgcn_s_setprio(1);
#pragma unroll
      for (int ks = 0; ks < 2; ++ks)
#pragma unroll
        for (int d = 0; d < 2; ++d)
#pragma unroll
          for (int j = 0; j < NJ; ++j)
            acc[d][j] = __builtin_amdgcn_mfma_f32_16x16x32_bf16(af[d][ks], bfr[j][ks], acc[d][j], 0, 0, 0);
      __builtin_amdgcn_s_setprio(0);
      // ---- ph1: certify {A1,A3}; read frags4-5; MFMA 2-3 ----
      if (pf) vwait<2>(); else vwait<0>();
      bar();
      if (pf) {
        stageB(2, kt + 1, nb);
        if constexpr (NJ >= 4) stageB(3, kt + 1, nb);
        stageA(0, kt + 1, nb);
      }
#pragma unroll
      for (int d = 4; d < 6; ++d)
#pragma unroll
        for (int ks = 0; ks < 2; ++ks) af[d][ks] = readA(ab, d, ks);
      __builtin_amdgcn_s_setprio(1);
#pragma unroll
      for (int ks = 0; ks < 2; ++ks)
#pragma unroll
        for (int d = 2; d < 4; ++d)
#pragma unroll
          for (int j = 0; j < NJ; ++j)
            acc[d][j] = __builtin_amdgcn_mfma_f32_16x16x32_bf16(af[d][ks], bfr[j][ks], acc[d][j], 0, 0, 0);
      __builtin_amdgcn_s_setprio(0);
      // ---- ph2: read frags6-7; MFMA 4-5 ----
      if (pf) stageA(2, kt + 1, nb);
#pragma unroll
      for (int d = 6; d < 8; ++d)
#pragma unroll
        for (int ks = 0; ks < 2; ++ks) af[d][ks] = readA(ab, d, ks);
      __builtin_amdgcn_s_setprio(1);
#pragma unroll
      for (int ks = 0; ks < 2; ++ks)
#pragma unroll
        for (int d = 4; d < 6; ++d)
#pragma unroll
          for (int j = 0; j < NJ; ++j)
            acc[d][j] = __builtin_amdgcn_mfma_f32_16x16x32_bf16(af[d][ks], bfr[j][ks], acc[d][j], 0, 0, 0);
      __builtin_amdgcn_s_setprio(0);
      // ---- ph3: MFMA 6-7 (frags resident) ----
      if (pf) { stageA(1, kt + 1, nb); stageA(3, kt + 1, nb); }
      __builtin_amdgcn_s_setprio(1);
#pragma unroll
      for (int ks = 0; ks < 2; ++ks)
#pragma unroll
        for (int d = 6; d < 8; ++d)
#pragma unroll
          for (int j = 0; j < NJ; ++j)
            acc[d][j] = __builtin_amdgcn_mfma_f32_16x16x32_bf16(af[d][ks], bfr[j][ks], acc[d][j], 0, 0, 0);
      __builtin_amdgcn_s_setprio(0);
    } else {
      // ---- BN=128, ph0: certify {B*,A0,A2}; read B + frags0-3; MFMA 0-3 ----
      vwait<2>(); bar();
      if (pf) { stageB(0, kt + 1, nb); stageB(1, kt + 1, nb); stageA(0, kt + 1, nb); }
#pragma unroll
      for (int j = 0; j < NJ; ++j)
#pragma unroll
        for (int ks = 0; ks < 2; ++ks) bfr[j][ks] = readB(bb, j, ks);
#pragma unroll
      for (int d = 0; d < 4; ++d)
#pragma unroll
        for (int ks = 0; ks < 2; ++ks) af[d][ks] = readA(ab, d, ks);
      __builtin_amdgcn_s_setprio(1);
#pragma unroll
      for (int ks = 0; ks < 2; ++ks)
#pragma unroll
        for (int d = 0; d < 4; ++d)
#pragma unroll
          for (int j = 0; j < NJ; ++j)
            acc[d][j] = __builtin_amdgcn_mfma_f32_16x16x32_bf16(af[d][ks], bfr[j][ks], acc[d][j], 0, 0, 0);
      __builtin_amdgcn_s_setprio(0);
      // ---- ph1: certify {A1,A3}; read frags4-7; MFMA 4-7 ----
      if (pf) vwait<3>(); else vwait<0>();
      bar();
      if (pf) { stageA(2, kt + 1, nb); stageA(1, kt + 1, nb); stageA(3, kt + 1, nb); }
#pragma unroll
      for (int d = 4; d < 8; ++d)
#pragma unroll
        for (int ks = 0; ks < 2; ++ks) af[d][ks] = readA(ab, d, ks);
      __builtin_amdgcn_s_setprio(1);
#pragma unroll
      for (int ks = 0; ks < 2; ++ks)
#pragma unroll
        for (int d = 4; d < 8; ++d)
#pragma unroll
          for (int j = 0; j < NJ; ++j)
            acc[d][j] = __builtin_amdgcn_mfma_f32_16x16x32_bf16(af[d][ks], bfr[j][ks], acc[d][j], 0, 0, 0);
      __builtin_amdgcn_s_setprio(0);
    }
  }

  // epilogue: C/D layout col=lane&15, row=(lane>>4)*4+r
#pragma unroll
  for (int i = 0; i < 8; ++i) {
    const int rbase = m0 + wr * 128 + i * 16 + ((lane >> 4) << 2);
#pragma unroll
    for (int j = 0; j < NJ; ++j) {
      const int cc = n0 + wc * WCN + j * 16 + (lane & 15);
      float bv = 0.f;
      if (BIAS) bv = bias[cc];
      bool vpath = false;
      if constexpr (VTW) vpath = (cc >= 2048);
      if (vpath) {
        // V columns: transposed store vtw[bh*64+dd][s] (4 contiguous s = uint2)
        const float v0 = acc[i][j][0] + bv, v1 = acc[i][j][1] + bv;
        const float v2 = acc[i][j][2] + bv, v3 = acc[i][j][3] + bv;
        const int d = cc - 2048;
        const int b = rbase >> 10, s = rbase & 1023;
        unsigned short* vp = vtw + ((size_t)(((b << 4) | (d >> 6)) << 6 | (d & 63))) * 1024 + s;
        uint2 st = { pkbf(v0, v1), pkbf(v2, v3) };
        *(uint2*)vp = st;
      } else {
#pragma unroll
        for (int r = 0; r < 4; ++r) {
          const int row = rbase + r;
          float v = acc[i][j][r] + bv;
          if (EMB)  v = v * 32.f + pos[(size_t)(row & (SS - 1)) * N + cc];
          if (RELU) v = fmaxf(v, 0.f);
          if (RESID) v += b2f(resid[(size_t)row * N + cc]);
          if (WF32)  outf[(size_t)row * N + cc] = v;
          if (WBF16) outb[(size_t)row * N + cc] = f2b(v);
        }
      }
    }
  }
}

// ---------------- flash attention, swapped-QK^T, counted-vmcnt pipelined staging ----------------
// Staging now uses the gemm2c-validated 2-barrier counted-vmcnt ladder: tiles kt,kt+1
// in flight; per iter {vwait<4> certify tile kt (tail vwait<0>); bar; compute; bar;
// stage(kt+2)}. Loads never drain to 0 mid-loop (removes the per-iter vmcnt(0) drain
// that __syncthreads emitted).
__global__ __launch_bounds__(256) void attn2(
    const unsigned short* __restrict__ qkv,   // [M][3072]: Q|K|V
    const unsigned short* __restrict__ vt,    // [bh][64][1024] = V^T per head
    unsigned short* __restrict__ O) {         // [M][1024]
  __shared__ __align__(1024) char smem[2 * 16384];   // dbuf x (K 8KB | VT 8KB)
  const int t = threadIdx.x, lane = t & 63, w = t >> 6;
  const int l31 = lane & 31, lg = lane >> 5;   // lane group (0/1)
  const int bh = (blockIdx.x << 4) | (blockIdx.y & 15);
  const int qt = blockIdx.y >> 4;
  const int b = bh >> 4, h = bh & 15;
  const size_t rowb = (size_t)b << 10;
  const int q0 = qt * 128 + w * 32;

  bf16x8_t qf[4];
  {
    const unsigned short* Qp = qkv + (rowb + q0 + l31) * 3072 + h * 64 + lg * 8;
#pragma unroll
    for (int dd = 0; dd < 4; ++dd) qf[dd] = *(const bf16x8_t*)(Qp + dd * 16);
  }

  f32x16_t oa0, oa1;
#pragma unroll
  for (int r = 0; r < 16; ++r) { oa0[r] = 0.f; oa1[r] = 0.f; }
  float m_run = -1e30f, l_run = 0.f;
  const float inv32 = 1.f / 32.f;

  const char* kglob = (const char*)qkv + ((size_t)1024 + h * 64) * 2;
  const char* vglob = (const char*)vt + (size_t)bh * 64 * 1024 * 2;

  auto stage = [&](int kt, int buf) {
    char* kbuf = smem + buf * 16384;
    char* vbuf = kbuf + 8192;
#pragma unroll
    for (int i = 0; i < 2; ++i) {
      const int chunk = w * 2 + i;                 // 0..7
      const int byteoff = chunk * 1024 + lane * 16;
      const int row = byteoff >> 7;                // 0..63
      const int scb = (byteoff & 127) ^ ((row & 7) << 4);
      gload16(kglob + (size_t)(rowb + kt * 64 + row) * 6144 + scb, kbuf + chunk * 1024);
      gload16(vglob + ((size_t)row * 1024 + kt * 64) * 2 + scb,    vbuf + chunk * 1024);
    }
  };

  // prologue: tiles 0 and 1 in flight (4 loads each per wave; Q loads are oldest)
  stage(0, 0);
  stage(1, 1);
  for (int kt = 0; kt < 16; ++kt) {
    const int c = kt & 1;
    if (kt == 15) vwait<0>(); else vwait<4>();   // certify tile kt; kt+1 stays in flight
    bar();
    const char* kbuf = smem + c * 16384;
    const char* vbuf = kbuf + 8192;

    f32x16_t p0, p1;
#pragma unroll
    for (int r = 0; r < 16; ++r) { p0[r] = 0.f; p1[r] = 0.f; }
    __builtin_amdgcn_s_setprio(1);
#pragma unroll
    for (int dd = 0; dd < 4; ++dd) {
      {
        const int row = l31;
        const int col = (dd * 32 + (lg << 4)) ^ ((row & 7) << 4);
        bf16x8_t kf = *(const bf16x8_t*)(kbuf + row * 128 + col);
        p0 = __builtin_amdgcn_mfma_f32_32x32x16_bf16(kf, qf[dd], p0, 0, 0, 0);
      }
      {
        const int row = 32 + l31;
        const int col = (dd * 32 + (lg << 4)) ^ ((row & 7) << 4);
        bf16x8_t kf = *(const bf16x8_t*)(kbuf + row * 128 + col);
        p1 = __builtin_amdgcn_mfma_f32_32x32x16_bf16(kf, qf[dd], p1, 0, 0, 0);
      }
    }
    __builtin_amdgcn_s_setprio(0);

    float mx = p0[0];
#pragma unroll
    for (int r = 1; r < 16; ++r) mx = fmaxf(mx, p0[r]);
#pragma unroll
    for (int r = 0; r < 16; ++r) mx = fmaxf(mx, p1[r]);
    mx = fmaxf(mx, __shfl_xor(mx, 32));
    const float mn = fmaxf(m_run, mx * inv32);
    const float fr = __expf(m_run - mn);
    m_run = mn;
    float sum = 0.f;
#pragma unroll
    for (int r = 0; r < 16; ++r) { const float e = __expf(p0[r] * inv32 - mn); p0[r] = e; sum += e; }
#pragma unroll
    for (int r = 0; r < 16; ++r) { const float e = __expf(p1[r] * inv32 - mn); p1[r] = e; sum += e; }
    sum += __shfl_xor(sum, 32);
    l_run = l_run * fr + sum;
#pragma unroll
    for (int r = 0; r < 16; ++r) { oa0[r] *= fr; oa1[r] *= fr; }

    const unsigned A0 = pkbf(p0[0], p0[1]),  B0 = pkbf(p0[2], p0[3]);
    const unsigned C0 = pkbf(p0[4], p0[5]),  D0 = pkbf(p0[6], p0[7]);
    const unsigned E0 = pkbf(p0[8], p0[9]),  F0 = pkbf(p0[10], p0[11]);
    const unsigned G0 = pkbf(p0[12], p0[13]), H0 = pkbf(p0[14], p0[15]);
    const unsigned A1 = pkbf(p1[0], p1[1]),  B1 = pkbf(p1[2], p1[3]);
    const unsigned C1 = pkbf(p1[4], p1[5]),  D1 = pkbf(p1[6], p1[7]);
    const unsigned E1 = pkbf(p1[8], p1[9]),  F1 = pkbf(p1[10], p1[11]);
    const unsigned G1 = pkbf(p1[12], p1[13]), H1 = pkbf(p1[14], p1[15]);
    const unsigned sA0 = __shfl_xor((int)A0, 32), sB0 = __shfl_xor((int)B0, 32);
    const unsigned sC0 = __shfl_xor((int)C0, 32), sD0 = __shfl_xor((int)D0, 32);
    const unsigned sE0 = __shfl_xor((int)E0, 32), sF0 = __shfl_xor((int)F0, 32);
    const unsigned sG0 = __shfl_xor((int)G0, 32), sH0 = __shfl_xor((int)H0, 32);
    const unsigned sA1 = __shfl_xor((int)A1, 32), sB1 = __shfl_xor((int)B1, 32);
    const unsigned sC1 = __shfl_xor((int)C1, 32), sD1 = __shfl_xor((int)D1, 32);
    const unsigned sE1 = __shfl_xor((int)E1, 32), sF1 = __shfl_xor((int)F1, 32);
    const unsigned sG1 = __shfl_xor((int)G1, 32), sH1 = __shfl_xor((int)H1, 32);
    const bool hi = (lg != 0);
    bf16x8_t pf[4];
    pf[0] = hi ? mk8(sC0, sD0, C0, D0) : mk8(A0, B0, sA0, sB0);
    pf[1] = hi ? mk8(sG0, sH0, G0, H0) : mk8(E0, F0, sE0, sF0);
    pf[2] = hi ? mk8(sC1, sD1, C1, D1) : mk8(A1, B1, sA1, sB1);
    pf[3] = hi ? mk8(sG1, sH1, G1, H1) : mk8(E1, F1, sE1, sF1);

    __builtin_amdgcn_s_setprio(1);
#pragma unroll
    for (int c2 = 0; c2 < 4; ++c2) {
      {
        const int row = l31;
        const int col = (c2 * 32 + (lg << 4)) ^ ((row & 7) << 4);
        bf16x8_t vf = *(const bf16x8_t*)(vbuf + row * 128 + col);
        oa0 = __builtin_amdgcn_mfma_f32_32x32x16_bf16(vf, pf[c2], oa0, 0, 0, 0);
      }
      {
        const int row = 32 + l31;
        const int col = (c2 * 32 + (lg << 4)) ^ ((row & 7) << 4);
        bf16x8_t vf = *(const bf16x8_t*)(vbuf + row * 128 + col);
        oa1 = __builtin_amdgcn_mfma_f32_32x32x16_bf16(vf, pf[c2], oa1, 0, 0, 0);
      }
    }
    __builtin_amdgcn_s_setprio(0);

    bar();                               // all waves done reading buf c
    if (kt + 2 < 16) stage(kt + 2, c);   // overwrite freed buffer; stays in flight
  }

  const float inv = 1.f / l_run;
  unsigned short* op = O + (rowb + q0 + l31) * 1024 + h * 64 + (lg << 2);
#pragma unroll
  for (int rg = 0; rg < 4; ++rg) {
    const unsigned u0 = pkbf(oa0[rg * 4 + 0] * inv, oa0[rg * 4 + 1] * inv);
    const unsigned u1 = pkbf(oa0[rg * 4 + 2] * inv, oa0[rg * 4 + 3] * inv);
    uint2 st = { u0, u1 };
    *(uint2*)(op + rg * 8) = st;
    const unsigned v0 = pkbf(oa1[rg * 4 + 0] * inv, oa1[rg * 4 + 1] * inv);
    const unsigned v1 = pkbf(oa1[rg * 4 + 2] * inv, oa1[rg * 4 + 3] * inv);
    uint2 st2 = { v0, v1 };
    *(uint2*)(op + 32 + rg * 8) = st2;
  }
}

// ---------------- LayerNorm: bf16 in -> bf16 out (+ optional fp32 out) ----------------
template<bool WOUT>
__global__ __launch_bounds__(256) void lnb_kernel(
    const unsigned short* __restrict__ yb, const float* __restrict__ g,
    const float* __restrict__ be,
    float* __restrict__ xf, unsigned short* __restrict__ xb) {
  const int row = blockIdx.x;
  const int t = threadIdx.x;
  const ushort4 u = ((const ushort4*)(yb + (size_t)row * HDIM))[t];
  float4 v = { b2f(u.x), b2f(u.y), b2f(u.z), b2f(u.w) };
  float s  = v.x + v.y + v.z + v.w;
  float ss = v.x*v.x + v.y*v.y + v.z*v.z + v.w*v.w;
#pragma unroll
  for (int m = 1; m < 64; m <<= 1) { s += __shfl_xor(s, m); ss += __shfl_xor(ss, m); }
  __shared__ float rs[4], rss[4];
  const int w = t >> 6, lane = t & 63;
  if (lane == 0) { rs[w] = s; rss[w] = ss; }
  __syncthreads();
  s  = rs[0] + rs[1] + rs[2] + rs[3];
  ss = rss[0] + rss[1] + rss[2] + rss[3];
  const float mean = s * (1.f / HDIM);
  const float inv = rsqrtf(ss * (1.f / HDIM) - mean * mean + 1e-5f);
  const int c = t * 4;
  const float4 gg = *(const float4*)(g + c);
  const float4 bb = *(const float4*)(be + c);
  float4 o;
  o.x = (v.x - mean) * inv * gg.x + bb.x;
  o.y = (v.y - mean) * inv * gg.y + bb.y;
  o.z = (v.z - mean) * inv * gg.z + bb.z;
  o.w = (v.w - mean) * inv * gg.w + bb.w;
  if (WOUT) ((float4*)(xf + (size_t)row * HDIM))[t] = o;
  ushort4 ob = { f2b(o.x), f2b(o.y), f2b(o.z), f2b(o.w) };
  ((ushort4*)(xb + (size_t)row * HDIM))[t] = ob;
}

// ---------------- host ----------------
extern "C" void kernel_launch(void* const* d_in, const int* in_sizes, int n_in,
                              void* d_out, int out_size, void* d_ws, size_t ws_size,
                              hipStream_t stream) {
  const float* input_x = (const float*)d_in[0];
  const float* emb_W   = (const float*)d_in[1];
  const float* emb_b   = (const float*)d_in[2];
  const float* pos_tab = (const float*)d_in[3];
  const float* Wq  = (const float*)d_in[4];
  const float* bq  = (const float*)d_in[5];
  const float* Wk  = (const float*)d_in[6];
  const float* bk  = (const float*)d_in[7];
  const float* Wv  = (const float*)d_in[8];
  const float* bv  = (const float*)d_in[9];
  const float* Wo  = (const float*)d_in[10];
  const float* bo  = (const float*)d_in[11];
  const float* ln1g = (const float*)d_in[12];
  const float* ln1b = (const float*)d_in[13];
  const float* W1  = (const float*)d_in[14];
  const float* b1  = (const float*)d_in[15];
  const float* W2  = (const float*)d_in[16];
  const float* b2  = (const float*)d_in[17];
  const float* ln2g = (const float*)d_in[18];
  const float* ln2b = (const float*)d_in[19];
  float* out = (float*)d_out;

  char* ws = (char*)d_ws;
  size_t off = 0;
  auto alloc = [&](size_t bytes) {
    char* p = ws + off;
    off += (bytes + 255) & ~(size_t)255;
    return p;
  };
  unsigned short* wqkvT = (unsigned short*)alloc((size_t)3072 * HDIM * 2);
  unsigned short* woT   = (unsigned short*)alloc((size_t)HDIM * HDIM * 2);
  unsigned short* w1T   = (unsigned short*)alloc((size_t)PFF * HDIM * 2);   // [PF][H]
  unsigned short* w2T   = (unsigned short*)alloc((size_t)HDIM * PFF * 2);   // [H][PF]
  unsigned short* embWT = (unsigned short*)alloc((size_t)HDIM * 256 * 2);   // [H][IN]
  float*          bqkv  = (float*)alloc(3072 * 4);
  unsigned short* inb   = (unsigned short*)alloc((size_t)MM * 256 * 2);
  unsigned short* xb    = (unsigned short*)alloc((size_t)MM * HDIM * 2);
  unsigned short* qkvb  = (unsigned short*)alloc((size_t)MM * 3072 * 2);    // 48MB
  unsigned short* vtb   = (unsigned short*)alloc((size_t)MM * HDIM * 2);    // 16MB
  unsigned short* ab    = (unsigned short*)alloc((size_t)MM * HDIM * 2);
  unsigned short* yb    = (unsigned short*)alloc((size_t)MM * HDIM * 2);    // pre-LN act (bf16)
  unsigned short* hb = qkvb;   // FFN hidden [M][4096] spans qkvb+vtb (both dead by FFN1)

  const dim3 blk256(256);
  const dim3 blk512(512);
  const dim3 tblk(32, 8);

  // prep
  cvt_bf16<<<dim3(MM * 256 / 4 / 256), blk256, 0, stream>>>(input_x, inb, MM * 256 / 4);
  transpose_bf16<<<dim3(HDIM / 32, 256 / 32), tblk, 0, stream>>>(emb_W, embWT, 256, HDIM);

  // embedding: x = (input @ embW + b)*32 + pos -> xb (bf16 only; residual stream is bf16)
  gemm2c<128, true, false, false, true, false, true, false><<<dim3(HDIM / 128, MM / 256), blk512, 0, stream>>>(
      inb, embWT, emb_b, nullptr, pos_tab, nullptr, xb, nullptr, MM, HDIM, 256);

  for (int l = 0; l < NLAYER; ++l) {
    const size_t wofs = (size_t)l * HDIM * HDIM;
    // all 6 weight transposes + bias concat in one launch
    prep_layer<<<dim3(12300), tblk, 0, stream>>>(
        Wq + wofs, Wk + wofs, Wv + wofs, Wo + wofs,
        W1 + (size_t)l * HDIM * PFF, W2 + (size_t)l * PFF * HDIM,
        bq + l * HDIM, bk + l * HDIM, bv + l * HDIM,
        wqkvT, woT, w1T, w2T, bqkv);

    // fused QKV GEMM (BN=128: 768 blocks = exactly 3 CU-rounds)
    gemm2c<128, true, false, false, false, false, true, true><<<dim3(3072 / 128, MM / 256), blk512, 0, stream>>>(
        xb, wqkvT, bqkv, nullptr, nullptr, nullptr, qkvb, vtb, MM, 3072, HDIM);

    // attention (counted-vmcnt pipelined staging)
    attn2<<<dim3(SS / 128, BB * NHEAD), blk256, 0, stream>>>(qkvb, vtb, ab);

    // O-proj + residual(bf16 xb) -> yb (bf16 pre-LN activation)
    gemm2c<128, true, false, true, false, false, true, false><<<dim3(HDIM / 128, MM / 256), blk512, 0, stream>>>(
        ab, woT, bo + l * HDIM, xb, nullptr, nullptr, yb, nullptr, MM, HDIM, HDIM);
    lnb_kernel<false><<<dim3(MM), blk256, 0, stream>>>(yb, ln1g + l * HDIM, ln1b + l * HDIM, out, xb);

    // FFN
    gemm2c<256, true, true, false, false, false, true, false><<<dim3(PFF / 256, MM / 256), blk512, 0, stream>>>(
        xb, w1T, b1 + (size_t)l * PFF, nullptr, nullptr, nullptr, hb, nullptr, MM, PFF, HDIM);
    gemm2c<128, true, false, true, false, false, true, false><<<dim3(HDIM / 128, MM / 256), blk512, 0, stream>>>(
        hb, w2T, b2 + l * HDIM, xb, nullptr, nullptr, yb, nullptr, MM, HDIM, PFF);
    if (l == NLAYER - 1)
      lnb_kernel<true><<<dim3(MM), blk256, 0, stream>>>(yb, ln2g + l * HDIM, ln2b + l * HDIM, out, xb);
    else
      lnb_kernel<false><<<dim3(MM), blk256, 0, stream>>>(yb, ln2g + l * HDIM, ln2b + l * HDIM, out, xb);
  }
  (void)in_sizes; (void)n_in; (void)out_size; (void)ws_size;
}

// Round 18
// 2063.001 us; speedup vs baseline: 1.0147x; 1.0147x over previous
//
#include <hip/hip_runtime.h>

// ---------------- constants ----------------
#define HDIM 1024
#define BB 8
#define SS 1024
#define NHEAD 16
#define PFF 4096
#define NLAYER 6
#define MM (BB*SS)   // 8192 rows

typedef __attribute__((ext_vector_type(8))) short bf16x8_t;
typedef __attribute__((ext_vector_type(4))) float f32x4_t;
typedef __attribute__((ext_vector_type(16))) float f32x16_t;

static __device__ __forceinline__ unsigned short f2b(float f) {
  unsigned int u = __float_as_uint(f);
  u += 0x7fffu + ((u >> 16) & 1u);      // RNE
  return (unsigned short)(u >> 16);
}

static __device__ __forceinline__ float b2f(unsigned short u) {
  return __uint_as_float(((unsigned)u) << 16);
}

static __device__ __forceinline__ unsigned pkbf(float lo, float hi) {
  unsigned r;
  asm("v_cvt_pk_bf16_f32 %0, %1, %2" : "=v"(r) : "v"(lo), "v"(hi));
  return r;
}

static __device__ __forceinline__ bf16x8_t mk8(unsigned a, unsigned b, unsigned c, unsigned d) {
  union { unsigned u[4]; bf16x8_t v; } x;
  x.u[0] = a; x.u[1] = b; x.u[2] = c; x.u[3] = d;
  return x.v;
}

static __device__ __forceinline__ void gload16(const void* g, void* l) {
  __builtin_amdgcn_global_load_lds((__attribute__((address_space(1))) void*)g,
                                   (__attribute__((address_space(3))) void*)l, 16, 0, 0);
}

template<int N>
static __device__ __forceinline__ void vwait() {
  asm volatile("s_waitcnt vmcnt(%0)" :: "n"(N) : "memory");
}

static __device__ __forceinline__ void bar() {
  asm volatile("" ::: "memory");
  __builtin_amdgcn_s_barrier();
  asm volatile("" ::: "memory");
}

// ---------------- fp32 -> bf16 convert ----------------
__global__ __launch_bounds__(256) void cvt_bf16(const float* __restrict__ in,
                                                unsigned short* __restrict__ o, int n4) {
  const int i = blockIdx.x * 256 + threadIdx.x;
  if (i < n4) {
    const float4 v = ((const float4*)in)[i];
    ushort4 ob = { f2b(v.x), f2b(v.y), f2b(v.z), f2b(v.w) };
    ((ushort4*)o)[i] = ob;
  }
}

// ---------------- transpose fp32 [R][C] -> bf16 [C][R] (emb prep only) ----------------
__global__ __launch_bounds__(256) void transpose_bf16(const float* __restrict__ in,
                                                      unsigned short* __restrict__ outT,
                                                      int R, int C) {
  __shared__ float tile[32][33];
  const int c0 = blockIdx.x * 32, r0 = blockIdx.y * 32;
  const int tx = threadIdx.x, ty = threadIdx.y;   // (32,8)
#pragma unroll
  for (int i = 0; i < 4; ++i)
    tile[ty + 8*i][tx] = in[(size_t)(r0 + ty + 8*i) * C + c0 + tx];
  __syncthreads();
#pragma unroll
  for (int i = 0; i < 4; ++i)
    outT[(size_t)(c0 + ty + 8*i) * R + r0 + tx] = f2b(tile[tx][ty + 8*i]);
}

// ---------------- per-layer prep: 6 weight transposes + bias concat in ONE launch ----------------
__global__ __launch_bounds__(256) void prep_layer(
    const float* __restrict__ Wq, const float* __restrict__ Wk,
    const float* __restrict__ Wv, const float* __restrict__ Wo,
    const float* __restrict__ W1, const float* __restrict__ W2,
    const float* __restrict__ bq, const float* __restrict__ bk,
    const float* __restrict__ bv,
    unsigned short* __restrict__ wqkvT, unsigned short* __restrict__ woT,
    unsigned short* __restrict__ w1T, unsigned short* __restrict__ w2T,
    float* __restrict__ bqkv) {
  const int id = blockIdx.x;
  const int tx = threadIdx.x, ty = threadIdx.y;   // (32,8)
  if (id >= 12288) {                               // bias concat (12 blocks x 256)
    const int i = (id - 12288) * 256 + ty * 32 + tx;
    bqkv[i] = (i < 1024) ? bq[i] : ((i < 2048) ? bk[i - 1024] : bv[i - 2048]);
    return;
  }
  __shared__ float tile[32][33];
  const float* in; unsigned short* outp; int R, C, tid;
  if (id < 1024)      { in = Wq; outp = wqkvT;           R = 1024; C = 1024; tid = id; }
  else if (id < 2048) { in = Wk; outp = wqkvT + 1048576; R = 1024; C = 1024; tid = id - 1024; }
  else if (id < 3072) { in = Wv; outp = wqkvT + 2097152; R = 1024; C = 1024; tid = id - 2048; }
  else if (id < 4096) { in = Wo; outp = woT;             R = 1024; C = 1024; tid = id - 3072; }
  else if (id < 8192) { in = W1; outp = w1T;             R = 1024; C = 4096; tid = id - 4096; }
  else                { in = W2; outp = w2T;             R = 4096; C = 1024; tid = id - 8192; }
  const int gxn = C >> 5;
  const int c0 = (tid % gxn) * 32, r0 = (tid / gxn) * 32;
#pragma unroll
  for (int i = 0; i < 4; ++i)
    tile[ty + 8*i][tx] = in[(size_t)(r0 + ty + 8*i) * C + c0 + tx];
  __syncthreads();
#pragma unroll
  for (int i = 0; i < 4; ++i)
    outp[(size_t)(c0 + ty + 8*i) * R + r0 + tx] = f2b(tile[tx][ty + 8*i]);
}

// ---------------- GEMM 256xBN, 8 waves (2x4), 16x16x32, pipelined 2-barrier K-tile ----------------
// R6/R8/R10-R16-verified schedule. BN in {128,192,256}.
template<int BN, bool BIAS, bool RELU, bool RESID, bool EMB, bool WF32, bool WBF16, bool VTW>
__global__ __launch_bounds__(512, 2) void gemm2c(
    const unsigned short* __restrict__ A,
    const unsigned short* __restrict__ Bt,
    const float* __restrict__ bias,
    const unsigned short* __restrict__ resid,   // bf16 residual stream
    const float* __restrict__ pos,
    float* __restrict__ outf,
    unsigned short* __restrict__ outb,
    unsigned short* __restrict__ vtw,
    int M, int N, int K) {
  constexpr int NJ = BN / 64;                    // B frags per wave (4, 3 or 2)
  constexpr int WCN = BN / 4;                    // per-wave col span
  constexpr int BUFSZ = 32768 + BN * 128;
  __shared__ __align__(1024) char smem[2 * BUFSZ];
  const int t = threadIdx.x, lane = t & 63, w = t >> 6;
  const int wr = w >> 2, wc = w & 3;             // 2x4 wave grid

  // bijective XCD swizzle (all grids divisible by 8)
  int flat = blockIdx.x + gridDim.x * blockIdx.y;
  const int cpx = (gridDim.x * gridDim.y) >> 3;
  flat = (flat & 7) * cpx + (flat >> 3);
  const int m0 = (flat / gridDim.x) * 256;
  const int n0 = (flat % gridDim.x) * BN;

  const f32x4_t z = {0.f, 0.f, 0.f, 0.f};
  f32x4_t acc[8][NJ];
#pragma unroll
  for (int i = 0; i < 8; ++i)
#pragma unroll
    for (int j = 0; j < NJ; ++j) acc[i][j] = z;

  auto stageA = [&](int i, int kt, int buf) {
    const int chunk = i * 8 + w;                 // band i = rows [64*i, +64)
    const int byteoff = chunk * 1024 + lane * 16;
    const int row = byteoff >> 7;
    const int scb = (byteoff & 127) ^ ((row & 7) << 4);
    gload16((const char*)A + ((size_t)(m0 + row) * K + (kt << 6)) * 2 + scb,
            smem + buf * BUFSZ + chunk * 1024);
  };
  auto stageB = [&](int i, int kt, int buf) {
    const int chunk = i * 8 + w;
    const int byteoff = chunk * 1024 + lane * 16;
    const int row = byteoff >> 7;
    const int scb = (byteoff & 127) ^ ((row & 7) << 4);
    gload16((const char*)Bt + ((size_t)(n0 + row) * K + (kt << 6)) * 2 + scb,
            smem + buf * BUFSZ + 32768 + chunk * 1024);
  };
  auto readA = [&](const char* ab, int fi, int ks) {
    const int row = wr * 128 + fi * 16 + (lane & 15);
    const int cb = ks * 64 + ((lane >> 4) << 4);
    return *(const bf16x8_t*)(ab + row * 128 + (cb ^ ((row & 7) << 4)));
  };
  auto readB = [&](const char* bb, int j, int ks) {
    const int row = wc * WCN + j * 16 + (lane & 15);
    const int cb = ks * 64 + ((lane >> 4) << 4);
    return *(const bf16x8_t*)(bb + row * 128 + (cb ^ ((row & 7) << 4)));
  };

  // prologue: tile 0 in need-order (B*, A0, A2, A1, A3)
  stageB(0, 0, 0); stageB(1, 0, 0);
  if constexpr (NJ >= 3) stageB(2, 0, 0);
  if constexpr (NJ >= 4) stageB(3, 0, 0);
  stageA(0, 0, 0); stageA(2, 0, 0); stageA(1, 0, 0); stageA(3, 0, 0);

  const int nkt = K >> 6;
  for (int kt = 0; kt < nkt; ++kt) {
    const char* ab = smem + (kt & 1) * BUFSZ;
    const char* bb = ab + 32768;
    const int nb = (kt & 1) ^ 1;
    const bool pf = (kt + 1 < nkt);
    bf16x8_t bfr[NJ][2], af[8][2];

    if constexpr (BN >= 192) {
      // ---- ph0: certify {B*,A0,A2}; read B + frags0-3; MFMA 0-1 ----
      vwait<2>(); bar();
      if (pf) { stageB(0, kt + 1, nb); stageB(1, kt + 1, nb); }
#pragma unroll
      for (int j = 0; j < NJ; ++j)
#pragma unroll
        for (int ks = 0; ks < 2; ++ks) bfr[j][ks] = readB(bb, j, ks);
#pragma unroll
      for (int d = 0; d < 4; ++d)
#pragma unroll
        for (int ks = 0; ks < 2; ++ks) af[d][ks] = readA(ab, d, ks);
      __builtin_amdgcn_s_setprio(1);
#pragma unroll
      for (int ks = 0; ks < 2; ++ks)
#pragma unroll
        for (int d = 0; d < 2; ++d)
#pragma unroll
          for (int j = 0; j < NJ; ++j)
            acc[d][j] = __builtin_amdgcn_mfma_f32_16x16x32_bf16(af[d][ks], bfr[j][ks], acc[d][j], 0, 0, 0);
      __builtin_amdgcn_s_setprio(0);
      // ---- ph1: certify {A1,A3}; read frags4-5; MFMA 2-3 ----
      if (pf) vwait<2>(); else vwait<0>();
      bar();
      if (pf) {
        stageB(2, kt + 1, nb);
        if constexpr (NJ >= 4) stageB(3, kt + 1, nb);
        stageA(0, kt + 1, nb);
      }
#pragma unroll
      for (int d = 4; d < 6; ++d)
#pragma unroll
        for (int ks = 0; ks < 2; ++ks) af[d][ks] = readA(ab, d, ks);
      __builtin_amdgcn_s_setprio(1);
#pragma unroll
      for (int ks = 0; ks < 2; ++ks)
#pragma unroll
        for (int d = 2; d < 4; ++d)
#pragma unroll
          for (int j = 0; j < NJ; ++j)
            acc[d][j] = __builtin_amdgcn_mfma_f32_16x16x32_bf16(af[d][ks], bfr[j][ks], acc[d][j], 0, 0, 0);
      __builtin_amdgcn_s_setprio(0);
      // ---- ph2: read frags6-7; MFMA 4-5 ----
      if (pf) stageA(2, kt + 1, nb);
#pragma unroll
      for (int d = 6; d < 8; ++d)
#pragma unroll
        for (int ks = 0; ks < 2; ++ks) af[d][ks] = readA(ab, d, ks);
      __builtin_amdgcn_s_setprio(1);
#pragma unroll
      for (int ks = 0; ks < 2; ++ks)
#pragma unroll
        for (int d = 4; d < 6; ++d)
#pragma unroll
          for (int j = 0; j < NJ; ++j)
            acc[d][j] = __builtin_amdgcn_mfma_f32_16x16x32_bf16(af[d][ks], bfr[j][ks], acc[d][j], 0, 0, 0);
      __builtin_amdgcn_s_setprio(0);
      // ---- ph3: MFMA 6-7 (frags resident) ----
      if (pf) { stageA(1, kt + 1, nb); stageA(3, kt + 1, nb); }
      __builtin_amdgcn_s_setprio(1);
#pragma unroll
      for (int ks = 0; ks < 2; ++ks)
#pragma unroll
        for (int d = 6; d < 8; ++d)
#pragma unroll
          for (int j = 0; j < NJ; ++j)
            acc[d][j] = __builtin_amdgcn_mfma_f32_16x16x32_bf16(af[d][ks], bfr[j][ks], acc[d][j], 0, 0, 0);
      __builtin_amdgcn_s_setprio(0);
    } else {
      // ---- BN=128, ph0: certify {B*,A0,A2}; read B + frags0-3; MFMA 0-3 ----
      vwait<2>(); bar();
      if (pf) { stageB(0, kt + 1, nb); stageB(1, kt + 1, nb); stageA(0, kt + 1, nb); }
#pragma unroll
      for (int j = 0; j < NJ; ++j)
#pragma unroll
        for (int ks = 0; ks < 2; ++ks) bfr[j][ks] = readB(bb, j, ks);
#pragma unroll
      for (int d = 0; d < 4; ++d)
#pragma unroll
        for (int ks = 0; ks < 2; ++ks) af[d][ks] = readA(ab, d, ks);
      __builtin_amdgcn_s_setprio(1);
#pragma unroll
      for (int ks = 0; ks < 2; ++ks)
#pragma unroll
        for (int d = 0; d < 4; ++d)
#pragma unroll
          for (int j = 0; j < NJ; ++j)
            acc[d][j] = __builtin_amdgcn_mfma_f32_16x16x32_bf16(af[d][ks], bfr[j][ks], acc[d][j], 0, 0, 0);
      __builtin_amdgcn_s_setprio(0);
      // ---- ph1: certify {A1,A3}; read frags4-7; MFMA 4-7 ----
      if (pf) vwait<3>(); else vwait<0>();
      bar();
      if (pf) { stageA(2, kt + 1, nb); stageA(1, kt + 1, nb); stageA(3, kt + 1, nb); }
#pragma unroll
      for (int d = 4; d < 8; ++d)
#pragma unroll
        for (int ks = 0; ks < 2; ++ks) af[d][ks] = readA(ab, d, ks);
      __builtin_amdgcn_s_setprio(1);
#pragma unroll
      for (int ks = 0; ks < 2; ++ks)
#pragma unroll
        for (int d = 4; d < 8; ++d)
#pragma unroll
          for (int j = 0; j < NJ; ++j)
            acc[d][j] = __builtin_amdgcn_mfma_f32_16x16x32_bf16(af[d][ks], bfr[j][ks], acc[d][j], 0, 0, 0);
      __builtin_amdgcn_s_setprio(0);
    }
  }

  // epilogue: C/D layout col=lane&15, row=(lane>>4)*4+r
#pragma unroll
  for (int i = 0; i < 8; ++i) {
    const int rbase = m0 + wr * 128 + i * 16 + ((lane >> 4) << 2);
#pragma unroll
    for (int j = 0; j < NJ; ++j) {
      const int cc = n0 + wc * WCN + j * 16 + (lane & 15);
      float bv = 0.f;
      if (BIAS) bv = bias[cc];
      bool vpath = false;
      if constexpr (VTW) vpath = (cc >= 2048);
      if (vpath) {
        // V columns: transposed store vtw[bh*64+dd][s] (4 contiguous s = uint2)
        const float v0 = acc[i][j][0] + bv, v1 = acc[i][j][1] + bv;
        const float v2 = acc[i][j][2] + bv, v3 = acc[i][j][3] + bv;
        const int d = cc - 2048;
        const int b = rbase >> 10, s = rbase & 1023;
        unsigned short* vp = vtw + ((size_t)(((b << 4) | (d >> 6)) << 6 | (d & 63))) * 1024 + s;
        uint2 st = { pkbf(v0, v1), pkbf(v2, v3) };
        *(uint2*)vp = st;
      } else {
#pragma unroll
        for (int r = 0; r < 4; ++r) {
          const int row = rbase + r;
          float v = acc[i][j][r] + bv;
          if (EMB)  v = v * 32.f + pos[(size_t)(row & (SS - 1)) * N + cc];
          if (RELU) v = fmaxf(v, 0.f);
          if (RESID) v += b2f(resid[(size_t)row * N + cc]);
          if (WF32)  outf[(size_t)row * N + cc] = v;
          if (WBF16) outb[(size_t)row * N + cc] = f2b(v);
        }
      }
    }
  }
}

// ---------------- flash attention, swapped-QK^T in-register softmax ----------------
// R15-verified kernel+grid pair: grid MUST be (SS/128, BB*NHEAD) = (8,128).
// Decode: head = (bx<<4)|(by&15) in [0,128), q-tile = by>>4 in [0,8).
__global__ __launch_bounds__(256) void attn2(
    const unsigned short* __restrict__ qkv,   // [M][3072]: Q|K|V
    const unsigned short* __restrict__ vt,    // [bh][64][1024] = V^T per head
    unsigned short* __restrict__ O) {         // [M][1024]
  __shared__ __align__(1024) char smem[2 * 16384];   // dbuf x (K 8KB | VT 8KB)
  const int t = threadIdx.x, lane = t & 63, w = t >> 6;
  const int l31 = lane & 31, lg = lane >> 5;   // lane group (0/1)
  const int bh = (blockIdx.x << 4) | (blockIdx.y & 15);
  const int qt = blockIdx.y >> 4;
  const int b = bh >> 4, h = bh & 15;
  const size_t rowb = (size_t)b << 10;
  const int q0 = qt * 128 + w * 32;

  bf16x8_t qf[4];
  {
    const unsigned short* Qp = qkv + (rowb + q0 + l31) * 3072 + h * 64 + lg * 8;
#pragma unroll
    for (int dd = 0; dd < 4; ++dd) qf[dd] = *(const bf16x8_t*)(Qp + dd * 16);
  }

  f32x16_t oa0, oa1;
#pragma unroll
  for (int r = 0; r < 16; ++r) { oa0[r] = 0.f; oa1[r] = 0.f; }
  float m_run = -1e30f, l_run = 0.f;
  const float inv32 = 1.f / 32.f;

  const char* kglob = (const char*)qkv + ((size_t)1024 + h * 64) * 2;
  const char* vglob = (const char*)vt + (size_t)bh * 64 * 1024 * 2;

  auto stage = [&](int kt, int buf) {
    char* kbuf = smem + buf * 16384;
    char* vbuf = kbuf + 8192;
#pragma unroll
    for (int i = 0; i < 2; ++i) {
      const int chunk = w * 2 + i;                 // 0..7
      const int byteoff = chunk * 1024 + lane * 16;
      const int row = byteoff >> 7;                // 0..63
      const int scb = (byteoff & 127) ^ ((row & 7) << 4);
      gload16(kglob + (size_t)(rowb + kt * 64 + row) * 6144 + scb, kbuf + chunk * 1024);
      gload16(vglob + ((size_t)row * 1024 + kt * 64) * 2 + scb,    vbuf + chunk * 1024);
    }
  };

  stage(0, 0);
  for (int kt = 0; kt < 16; ++kt) {
    const int cb = kt & 1;
    __syncthreads();
    if (kt < 15) stage(kt + 1, cb ^ 1);
    const char* kbuf = smem + cb * 16384;
    const char* vbuf = kbuf + 8192;

    f32x16_t p0, p1;
#pragma unroll
    for (int r = 0; r < 16; ++r) { p0[r] = 0.f; p1[r] = 0.f; }
    __builtin_amdgcn_s_setprio(1);
#pragma unroll
    for (int dd = 0; dd < 4; ++dd) {
      {
        const int row = l31;
        const int col = (dd * 32 + (lg << 4)) ^ ((row & 7) << 4);
        bf16x8_t kf = *(const bf16x8_t*)(kbuf + row * 128 + col);
        p0 = __builtin_amdgcn_mfma_f32_32x32x16_bf16(kf, qf[dd], p0, 0, 0, 0);
      }
      {
        const int row = 32 + l31;
        const int col = (dd * 32 + (lg << 4)) ^ ((row & 7) << 4);
        bf16x8_t kf = *(const bf16x8_t*)(kbuf + row * 128 + col);
        p1 = __builtin_amdgcn_mfma_f32_32x32x16_bf16(kf, qf[dd], p1, 0, 0, 0);
      }
    }
    __builtin_amdgcn_s_setprio(0);

    float mx = p0[0];
#pragma unroll
    for (int r = 1; r < 16; ++r) mx = fmaxf(mx, p0[r]);
#pragma unroll
    for (int r = 0; r < 16; ++r) mx = fmaxf(mx, p1[r]);
    mx = fmaxf(mx, __shfl_xor(mx, 32));
    const float mn = fmaxf(m_run, mx * inv32);
    const float fr = __expf(m_run - mn);
    m_run = mn;
    float sum = 0.f;
#pragma unroll
    for (int r = 0; r < 16; ++r) { const float e = __expf(p0[r] * inv32 - mn); p0[r] = e; sum += e; }
#pragma unroll
    for (int r = 0; r < 16; ++r) { const float e = __expf(p1[r] * inv32 - mn); p1[r] = e; sum += e; }
    sum += __shfl_xor(sum, 32);
    l_run = l_run * fr + sum;
#pragma unroll
    for (int r = 0; r < 16; ++r) { oa0[r] *= fr; oa1[r] *= fr; }

    const unsigned A0 = pkbf(p0[0], p0[1]),  B0 = pkbf(p0[2], p0[3]);
    const unsigned C0 = pkbf(p0[4], p0[5]),  D0 = pkbf(p0[6], p0[7]);
    const unsigned E0 = pkbf(p0[8], p0[9]),  F0 = pkbf(p0[10], p0[11]);
    const unsigned G0 = pkbf(p0[12], p0[13]), H0 = pkbf(p0[14], p0[15]);
    const unsigned A1 = pkbf(p1[0], p1[1]),  B1 = pkbf(p1[2], p1[3]);
    const unsigned C1 = pkbf(p1[4], p1[5]),  D1 = pkbf(p1[6], p1[7]);
    const unsigned E1 = pkbf(p1[8], p1[9]),  F1 = pkbf(p1[10], p1[11]);
    const unsigned G1 = pkbf(p1[12], p1[13]), H1 = pkbf(p1[14], p1[15]);
    const unsigned sA0 = __shfl_xor((int)A0, 32), sB0 = __shfl_xor((int)B0, 32);
    const unsigned sC0 = __shfl_xor((int)C0, 32), sD0 = __shfl_xor((int)D0, 32);
    const unsigned sE0 = __shfl_xor((int)E0, 32), sF0 = __shfl_xor((int)F0, 32);
    const unsigned sG0 = __shfl_xor((int)G0, 32), sH0 = __shfl_xor((int)H0, 32);
    const unsigned sA1 = __shfl_xor((int)A1, 32), sB1 = __shfl_xor((int)B1, 32);
    const unsigned sC1 = __shfl_xor((int)C1, 32), sD1 = __shfl_xor((int)D1, 32);
    const unsigned sE1 = __shfl_xor((int)E1, 32), sF1 = __shfl_xor((int)F1, 32);
    const unsigned sG1 = __shfl_xor((int)G1, 32), sH1 = __shfl_xor((int)H1, 32);
    const bool hi = (lg != 0);
    bf16x8_t pf[4];
    pf[0] = hi ? mk8(sC0, sD0, C0, D0) : mk8(A0, B0, sA0, sB0);
    pf[1] = hi ? mk8(sG0, sH0, G0, H0) : mk8(E0, F0, sE0, sF0);
    pf[2] = hi ? mk8(sC1, sD1, C1, D1) : mk8(A1, B1, sA1, sB1);
    pf[3] = hi ? mk8(sG1, sH1, G1, H1) : mk8(E1, F1, sE1, sF1);

    __builtin_amdgcn_s_setprio(1);
#pragma unroll
    for (int c = 0; c < 4; ++c) {
      {
        const int row = l31;
        const int col = (c * 32 + (lg << 4)) ^ ((row & 7) << 4);
        bf16x8_t vf = *(const bf16x8_t*)(vbuf + row * 128 + col);
        oa0 = __builtin_amdgcn_mfma_f32_32x32x16_bf16(vf, pf[c], oa0, 0, 0, 0);
      }
      {
        const int row = 32 + l31;
        const int col = (c * 32 + (lg << 4)) ^ ((row & 7) << 4);
        bf16x8_t vf = *(const bf16x8_t*)(vbuf + row * 128 + col);
        oa1 = __builtin_amdgcn_mfma_f32_32x32x16_bf16(vf, pf[c], oa1, 0, 0, 0);
      }
    }
    __builtin_amdgcn_s_setprio(0);
  }

  const float inv = 1.f / l_run;
  unsigned short* op = O + (rowb + q0 + l31) * 1024 + h * 64 + (lg << 2);
#pragma unroll
  for (int rg = 0; rg < 4; ++rg) {
    const unsigned u0 = pkbf(oa0[rg * 4 + 0] * inv, oa0[rg * 4 + 1] * inv);
    const unsigned u1 = pkbf(oa0[rg * 4 + 2] * inv, oa0[rg * 4 + 3] * inv);
    uint2 st = { u0, u1 };
    *(uint2*)(op + rg * 8) = st;
    const unsigned v0 = pkbf(oa1[rg * 4 + 0] * inv, oa1[rg * 4 + 1] * inv);
    const unsigned v1 = pkbf(oa1[rg * 4 + 2] * inv, oa1[rg * 4 + 3] * inv);
    uint2 st2 = { v0, v1 };
    *(uint2*)(op + 32 + rg * 8) = st2;
  }
}

// ---------------- LayerNorm: bf16 in -> bf16 out (+ optional fp32 out) ----------------
template<bool WOUT>
__global__ __launch_bounds__(256) void lnb_kernel(
    const unsigned short* __restrict__ yb, const float* __restrict__ g,
    const float* __restrict__ be,
    float* __restrict__ xf, unsigned short* __restrict__ xb) {
  const int row = blockIdx.x;
  const int t = threadIdx.x;
  const ushort4 u = ((const ushort4*)(yb + (size_t)row * HDIM))[t];
  float4 v = { b2f(u.x), b2f(u.y), b2f(u.z), b2f(u.w) };
  float s  = v.x + v.y + v.z + v.w;
  float ss = v.x*v.x + v.y*v.y + v.z*v.z + v.w*v.w;
#pragma unroll
  for (int m = 1; m < 64; m <<= 1) { s += __shfl_xor(s, m); ss += __shfl_xor(ss, m); }
  __shared__ float rs[4], rss[4];
  const int w = t >> 6, lane = t & 63;
  if (lane == 0) { rs[w] = s; rss[w] = ss; }
  __syncthreads();
  s  = rs[0] + rs[1] + rs[2] + rs[3];
  ss = rss[0] + rss[1] + rss[2] + rss[3];
  const float mean = s * (1.f / HDIM);
  const float inv = rsqrtf(ss * (1.f / HDIM) - mean * mean + 1e-5f);
  const int c = t * 4;
  const float4 gg = *(const float4*)(g + c);
  const float4 bb = *(const float4*)(be + c);
  float4 o;
  o.x = (v.x - mean) * inv * gg.x + bb.x;
  o.y = (v.y - mean) * inv * gg.y + bb.y;
  o.z = (v.z - mean) * inv * gg.z + bb.z;
  o.w = (v.w - mean) * inv * gg.w + bb.w;
  if (WOUT) ((float4*)(xf + (size_t)row * HDIM))[t] = o;
  ushort4 ob = { f2b(o.x), f2b(o.y), f2b(o.z), f2b(o.w) };
  ((ushort4*)(xb + (size_t)row * HDIM))[t] = ob;
}

// ---------------- host ----------------
extern "C" void kernel_launch(void* const* d_in, const int* in_sizes, int n_in,
                              void* d_out, int out_size, void* d_ws, size_t ws_size,
                              hipStream_t stream) {
  const float* input_x = (const float*)d_in[0];
  const float* emb_W   = (const float*)d_in[1];
  const float* emb_b   = (const float*)d_in[2];
  const float* pos_tab = (const float*)d_in[3];
  const float* Wq  = (const float*)d_in[4];
  const float* bq  = (const float*)d_in[5];
  const float* Wk  = (const float*)d_in[6];
  const float* bk  = (const float*)d_in[7];
  const float* Wv  = (const float*)d_in[8];
  const float* bv  = (const float*)d_in[9];
  const float* Wo  = (const float*)d_in[10];
  const float* bo  = (const float*)d_in[11];
  const float* ln1g = (const float*)d_in[12];
  const float* ln1b = (const float*)d_in[13];
  const float* W1  = (const float*)d_in[14];
  const float* b1  = (const float*)d_in[15];
  const float* W2  = (const float*)d_in[16];
  const float* b2  = (const float*)d_in[17];
  const float* ln2g = (const float*)d_in[18];
  const float* ln2b = (const float*)d_in[19];
  float* out = (float*)d_out;

  char* ws = (char*)d_ws;
  size_t off = 0;
  auto alloc = [&](size_t bytes) {
    char* p = ws + off;
    off += (bytes + 255) & ~(size_t)255;
    return p;
  };
  unsigned short* wqkvT = (unsigned short*)alloc((size_t)3072 * HDIM * 2);
  unsigned short* woT   = (unsigned short*)alloc((size_t)HDIM * HDIM * 2);
  unsigned short* w1T   = (unsigned short*)alloc((size_t)PFF * HDIM * 2);   // [PF][H]
  unsigned short* w2T   = (unsigned short*)alloc((size_t)HDIM * PFF * 2);   // [H][PF]
  unsigned short* embWT = (unsigned short*)alloc((size_t)HDIM * 256 * 2);   // [H][IN]
  float*          bqkv  = (float*)alloc(3072 * 4);
  unsigned short* inb   = (unsigned short*)alloc((size_t)MM * 256 * 2);
  unsigned short* xb    = (unsigned short*)alloc((size_t)MM * HDIM * 2);
  unsigned short* qkvb  = (unsigned short*)alloc((size_t)MM * 3072 * 2);    // 48MB
  unsigned short* vtb   = (unsigned short*)alloc((size_t)MM * HDIM * 2);    // 16MB
  unsigned short* ab    = (unsigned short*)alloc((size_t)MM * HDIM * 2);
  unsigned short* yb    = (unsigned short*)alloc((size_t)MM * HDIM * 2);    // pre-LN act (bf16)
  unsigned short* hb = qkvb;   // FFN hidden [M][4096] spans qkvb+vtb (both dead by FFN1)

  const dim3 blk256(256);
  const dim3 blk512(512);
  const dim3 tblk(32, 8);

  // prep
  cvt_bf16<<<dim3(MM * 256 / 4 / 256), blk256, 0, stream>>>(input_x, inb, MM * 256 / 4);
  transpose_bf16<<<dim3(HDIM / 32, 256 / 32), tblk, 0, stream>>>(emb_W, embWT, 256, HDIM);

  // embedding: x = (input @ embW + b)*32 + pos -> xb (bf16 only; residual stream is bf16)
  gemm2c<128, true, false, false, true, false, true, false><<<dim3(HDIM / 128, MM / 256), blk512, 0, stream>>>(
      inb, embWT, emb_b, nullptr, pos_tab, nullptr, xb, nullptr, MM, HDIM, 256);

  for (int l = 0; l < NLAYER; ++l) {
    const size_t wofs = (size_t)l * HDIM * HDIM;
    // all 6 weight transposes + bias concat in one launch
    prep_layer<<<dim3(12300), tblk, 0, stream>>>(
        Wq + wofs, Wk + wofs, Wv + wofs, Wo + wofs,
        W1 + (size_t)l * HDIM * PFF, W2 + (size_t)l * PFF * HDIM,
        bq + l * HDIM, bk + l * HDIM, bv + l * HDIM,
        wqkvT, woT, w1T, w2T, bqkv);

    // fused QKV GEMM (BN=192, grid 512 = exactly 2 CU-rounds; R12-best config)
    gemm2c<192, true, false, false, false, false, true, true><<<dim3(3072 / 192, MM / 256), blk512, 0, stream>>>(
        xb, wqkvT, bqkv, nullptr, nullptr, nullptr, qkvb, vtb, MM, 3072, HDIM);

    // attention (XCD head-grouped; grid (8,128) matches in-kernel decode)
    attn2<<<dim3(SS / 128, BB * NHEAD), blk256, 0, stream>>>(qkvb, vtb, ab);

    // O-proj + residual(bf16 xb) -> yb (bf16 pre-LN activation)
    gemm2c<128, true, false, true, false, false, true, false><<<dim3(HDIM / 128, MM / 256), blk512, 0, stream>>>(
        ab, woT, bo + l * HDIM, xb, nullptr, nullptr, yb, nullptr, MM, HDIM, HDIM);
    lnb_kernel<false><<<dim3(MM), blk256, 0, stream>>>(yb, ln1g + l * HDIM, ln1b + l * HDIM, out, xb);

    // FFN
    gemm2c<256, true, true, false, false, false, true, false><<<dim3(PFF / 256, MM / 256), blk512, 0, stream>>>(
        xb, w1T, b1 + (size_t)l * PFF, nullptr, nullptr, nullptr, hb, nullptr, MM, PFF, HDIM);
    gemm2c<128, true, false, true, false, false, true, false><<<dim3(HDIM / 128, MM / 256), blk512, 0, stream>>>(
        hb, w2T, b2 + l * HDIM, xb, nullptr, nullptr, yb, nullptr, MM, HDIM, PFF);
    if (l == NLAYER - 1)
      lnb_kernel<true><<<dim3(MM), blk256, 0, stream>>>(yb, ln2g + l * HDIM, ln2b + l * HDIM, out, xb);
    else
      lnb_kernel<false><<<dim3(MM), blk256, 0, stream>>>(yb, ln2g + l * HDIM, ln2b + l * HDIM, out, xb);
  }
  (void)in_sizes; (void)n_in; (void)out_size; (void)ws_size;
}